// Round 8
// baseline (161.242 us; speedup 1.0000x reference)
//
#include <hip/hip_runtime.h>

// SSIM loss — fused separable-conv tile kernel, v8.
// vs v7: v-pass rebalanced to 252/256 threads (42 cols x 6 segs, sizes
// {6,6,5,5,5,5}) — MACs now issue on 4 waves not 3; all global loads per
// thread (<=32 dwords) hoisted into registers BEFORE the conv crunch so
// L2/HBM latency amortizes over ~32 in-flight loads (v7: ~1-iter distance,
// VGPR 40 blocked hoisting). h-pass prefetches both channel windows.
// Packed (s,d) v_pk_fma math, single work barrier, 24KB LDS retained.

typedef float v2f __attribute__((ext_vector_type(2)));

#define IMG   512
#define NIMG  48
#define TW    32
#define TH    32
#define HSTR  46          // col stride in v2f units; row = 368B (b128-aligned)
#define TILES 16
#define NBLOCKS (NIMG * TILES * TILES)  // 12288

// exp(-(k-5)^2/4.5), unnormalized, symmetric.
#define G0 0.0038659204f
#define G1 0.0285655010f
#define G2 0.1353352832f
#define G3 0.4111123050f
#define G4 0.8007374029f
#define G5 1.0f

template<int SZ>
__device__ __forceinline__ void vconv_store(
    const float* __restrict__ ra, const float* __restrict__ rb,
    const float* __restrict__ gw, v2f (*sh2)[TH][HSTR], int rs, int c)
{
    v2f a0[SZ], a1[SZ];
#pragma unroll
    for (int r = 0; r < SZ; ++r) { a0[r] = (v2f){0.f, 0.f}; a1[r] = (v2f){0.f, 0.f}; }
#pragma unroll
    for (int j = 0; j < SZ + 10; ++j) {
        v2f w0 = (v2f){ra[j] + rb[j], ra[j] - rb[j]};
        v2f w1 = w0 * w0;
#pragma unroll
        for (int r = 0; r < SZ; ++r) {
            int k = j - r;
            if (k >= 0 && k <= 10) {
                const v2f wv = {gw[k], gw[k]};
                a0[r] = __builtin_elementwise_fma(w0, wv, a0[r]);
                a1[r] = __builtin_elementwise_fma(w1, wv, a1[r]);
            }
        }
    }
#pragma unroll
    for (int r = 0; r < SZ; ++r) {
        sh2[0][rs + r][c] = a0[r];
        sh2[1][rs + r][c] = a1[r];
    }
}

__global__ __launch_bounds__(256, 6) void ssim_tile_kernel(
    const float* __restrict__ img1, const float* __restrict__ img2,
    float* __restrict__ partials)
{
    __shared__ v2f sh2[2][TH][HSTR];     // [mu|x][row][padded-col] pairs, 23552B
    __shared__ float s_part[4];

    const float gw[11] = {G0,G1,G2,G3,G4,G5,G4,G3,G2,G1,G0};

    const int tid = threadIdx.x;
    const int tx0 = blockIdx.x * TW - 5;
    const int ty0 = blockIdx.y * TH - 5;
    const float* __restrict__ p1 = img1 + (size_t)blockIdx.z * (IMG * IMG);
    const float* __restrict__ p2 = img2 + (size_t)blockIdx.z * (IMG * IMG);

    // ===== v-pass: 252 threads = 42 cols x 6 segs, sizes {6,6,5,5,5,5} =====
    if (tid < 252) {
        const int c   = tid % 42;
        const int seg = tid / 42;
        const int sz  = (seg < 2) ? 6 : 5;
        const int rs  = (seg < 2) ? seg * 6 : 12 + (seg - 2) * 5;
        const int nin = sz + 10;
        const int gc  = tx0 + c;
        const int gr0 = ty0 + rs;

        float ra[16], rb[16];
        const bool interior = (blockIdx.x >= 1) && (blockIdx.x <= TILES - 2) &&
                              (blockIdx.y >= 1) && (blockIdx.y <= TILES - 2);
        if (interior) {
            const float* q1 = p1 + (size_t)gr0 * IMG + gc;
            const float* q2 = p2 + (size_t)gr0 * IMG + gc;
#pragma unroll
            for (int j = 0; j < 16; ++j) {
                if (j < nin) { ra[j] = q1[j * IMG]; rb[j] = q2[j * IMG]; }
            }
        } else {
            const bool cok = (unsigned)gc < IMG;
#pragma unroll
            for (int j = 0; j < 16; ++j) {
                if (j < nin) {
                    int gr = gr0 + j;
                    bool ok = cok && ((unsigned)gr < IMG);
                    ra[j] = ok ? p1[(size_t)gr * IMG + gc] : 0.f;
                    rb[j] = ok ? p2[(size_t)gr * IMG + gc] : 0.f;
                }
            }
        }
        if (sz == 6) vconv_store<6>(ra, rb, gw, sh2, rs, c);
        else         vconv_store<5>(ra, rb, gw, sh2, rs, c);
    }
    __syncthreads();

    // ===== h-pass: 256 threads = 32 rows x 8 groups of 4 cols =====
    const int row = tid >> 3;
    const int c0  = (tid & 7) * 4;       // even -> 32B offset -> b128-aligned
    v2f am[4], ax[4];
    {
        v2f hb0[14], hb1[14];
        {
            const float4* s0 = (const float4*)&sh2[0][row][c0];
            const float4* s1 = (const float4*)&sh2[1][row][c0];
#pragma unroll
            for (int q = 0; q < 7; ++q) ((float4*)hb0)[q] = s0[q];
#pragma unroll
            for (int q = 0; q < 7; ++q) ((float4*)hb1)[q] = s1[q];
        }
#pragma unroll
        for (int i = 0; i < 4; ++i) {
            v2f s = {0.f, 0.f};
#pragma unroll
            for (int k = 0; k < 11; ++k) {
                const v2f wv = {gw[k], gw[k]};
                s = __builtin_elementwise_fma(wv, hb0[i + k], s);
            }
            am[i] = s;
        }
#pragma unroll
        for (int i = 0; i < 4; ++i) {
            v2f s = {0.f, 0.f};
#pragma unroll
            for (int k = 0; k < 11; ++k) {
                const v2f wv = {gw[k], gw[k]};
                s = __builtin_elementwise_fma(wv, hb1[i + k], s);
            }
            ax[i] = s;
        }
    }

    // ---- SSIM from (s,d) algebra ----
    const float C1 = 1.0e-4f, C2 = 9.0e-4f;
    float local = 0.f;
#pragma unroll
    for (int i = 0; i < 4; ++i) {
        v2f mu = am[i];
        v2f mu2 = mu * mu;                        // pk_mul: (ms^2, md^2)
        float sum2 = 0.5f  * (mu2[0] + mu2[1]);   // mu1^2 + mu2^2
        float m12  = 0.25f * (mu2[0] - mu2[1]);   // mu1 * mu2
        v2f xx = ax[i];
        float xsum = 0.5f  * (xx[0] + xx[1]);     // x11 + x22
        float x12  = 0.25f * (xx[0] - xx[1]);
        float sg12  = x12 - m12;
        float sgsum = xsum - sum2;                // sigma1_sq + sigma2_sq
        float num = (2.f * m12 + C1) * (2.f * sg12 + C2);
        float den = (sum2 + C1) * (sgsum + C2);
        local = fmaf(num, __builtin_amdgcn_rcpf(den), local);
    }

#pragma unroll
    for (int off = 32; off > 0; off >>= 1)
        local += __shfl_down(local, off, 64);
    if ((tid & 63) == 0) s_part[tid >> 6] = local;
    __syncthreads();
    if (tid == 0) {
        int bidx = (blockIdx.z * gridDim.y + blockIdx.y) * gridDim.x + blockIdx.x;
        partials[bidx] = s_part[0] + s_part[1] + s_part[2] + s_part[3];
    }
}

__global__ __launch_bounds__(256) void ssim_final_kernel(
    const float* __restrict__ partials, float* __restrict__ out)
{
    __shared__ double sp[4];
    double acc = 0.0;
    for (int i = threadIdx.x; i < NBLOCKS; i += 256)
        acc += (double)partials[i];
#pragma unroll
    for (int off = 32; off > 0; off >>= 1)
        acc += __shfl_down(acc, off, 64);
    if ((threadIdx.x & 63) == 0) sp[threadIdx.x >> 6] = acc;
    __syncthreads();
    if (threadIdx.x == 0) {
        double total = sp[0] + sp[1] + sp[2] + sp[3];
        out[0] = (float)(1.0 - total / (double)((size_t)NIMG * IMG * IMG));
    }
}

extern "C" void kernel_launch(void* const* d_in, const int* in_sizes, int n_in,
                              void* d_out, int out_size, void* d_ws, size_t ws_size,
                              hipStream_t stream) {
    const float* img1 = (const float*)d_in[0];
    const float* img2 = (const float*)d_in[1];
    float* out = (float*)d_out;
    float* partials = (float*)d_ws;   // NBLOCKS floats, fully rewritten each call

    dim3 grid(TILES, TILES, NIMG);
    ssim_tile_kernel<<<grid, dim3(256), 0, stream>>>(img1, img2, partials);
    ssim_final_kernel<<<1, dim3(256), 0, stream>>>(partials, out);
}